// Round 1
// baseline (248.716 us; speedup 1.0000x reference)
//
#include <hip/hip_runtime.h>
#include <math.h>

#define NCLS 80
#define NA 8400
#define NB 32
#define NO 144
#define PRE_TOPK 1000
#define MAX_DET 100

// ---------------- Kernel 1: decode (DFL + sigmoid max/argmax) ----------------
__global__ __launch_bounds__(256) void k_decode(
    const float* __restrict__ p3, const float* __restrict__ p4, const float* __restrict__ p5,
    float* __restrict__ conf, int* __restrict__ clsid, float* __restrict__ box)
{
    int tid = blockIdx.x * 256 + threadIdx.x;
    if (tid >= NB * NA) return;
    int b = tid / NA;
    int a = tid - b * NA;

    const float* src; int hw, pos; float ax, ay, stride;
    if (a < 6400)      { src = p3; hw = 6400; pos = a;        ax = (float)(pos % 80) + 0.5f; ay = (float)(pos / 80) + 0.5f; stride = 8.f;  }
    else if (a < 8000) { src = p4; hw = 1600; pos = a - 6400; ax = (float)(pos % 40) + 0.5f; ay = (float)(pos / 40) + 0.5f; stride = 16.f; }
    else               { src = p5; hw = 400;  pos = a - 8000; ax = (float)(pos % 20) + 0.5f; ay = (float)(pos / 20) + 0.5f; stride = 32.f; }

    const float* base = src + (size_t)b * NO * hw + pos;

    // DFL: softmax over 16 bins per side, dot with arange(16)
    float dist[4];
    #pragma unroll
    for (int s4 = 0; s4 < 4; ++s4) {
        float v[16]; float m = -INFINITY;
        #pragma unroll
        for (int r = 0; r < 16; ++r) { v[r] = base[(size_t)(s4 * 16 + r) * hw]; m = fmaxf(m, v[r]); }
        float sum = 0.f;
        #pragma unroll
        for (int r = 0; r < 16; ++r) { v[r] = expf(v[r] - m); sum += v[r]; }
        float d = 0.f;
        #pragma unroll
        for (int r = 0; r < 16; ++r) { d += (v[r] / sum) * (float)r; }
        dist[s4] = d;
    }

    // box decode, exact ref op order
    float x1 = ax - dist[0], y1 = ay - dist[1];
    float x2 = ax + dist[2], y2 = ay + dist[3];
    float cx = ((x1 + x2) * 0.5f) * stride;
    float cy = ((y1 + y2) * 0.5f) * stride;
    float w  = (x2 - x1) * stride;
    float h  = (y2 - y1) * stride;

    // class scores: sigmoid in f32, max + first-index argmax (matches jnp semantics)
    float best = -1.0f; int bid = 0;
    for (int c = 0; c < NCLS; ++c) {
        float x = base[(size_t)(64 + c) * hw];
        float s = 1.0f / (1.0f + expf(-x));
        if (s > best) { best = s; bid = c; }
    }

    conf[tid] = best;
    clsid[tid] = bid;
    box[(size_t)tid * 4 + 0] = cx;
    box[(size_t)tid * 4 + 1] = cy;
    box[(size_t)tid * 4 + 2] = w;
    box[(size_t)tid * 4 + 3] = h;
}

// ---------------- Kernel 2: exact stable top-1000 per batch ----------------
__device__ __forceinline__ uint32_t ord_bits(float f) {
    uint32_t u = __float_as_uint(f);
    return (u & 0x80000000u) ? ~u : (u | 0x80000000u);
}

__global__ __launch_bounds__(1024) void k_topk(
    const float* __restrict__ conf, const float* __restrict__ box, const int* __restrict__ clsid,
    float* __restrict__ topv, float* __restrict__ bxyxy, int* __restrict__ topcls)
{
    int b = blockIdx.x;
    int t = threadIdx.x;

    __shared__ uint32_t ob[NA];          // 33.6 KB
    __shared__ uint32_t hist[256];
    __shared__ uint64_t sbuf[1024];      // 8 KB
    __shared__ uint64_t s_prefix;
    __shared__ int s_k;
    __shared__ int s_cnt;

    const float* cf = conf + (size_t)b * NA;
    for (int i = t; i < NA; i += 1024) {
        float c = cf[i];
        float cm = (c > 0.25f) ? c : -1.0f;
        ob[i] = ord_bits(cm);
    }
    if (t == 0) { s_prefix = 0; s_k = PRE_TOPK; s_cnt = 0; }
    sbuf[t] = 0;
    __syncthreads();

    // radix-select the exact rank-1000 key (keys unique: index embedded)
    for (int pass = 0; pass < 8; ++pass) {
        int shift = 56 - 8 * pass;
        if (t < 256) hist[t] = 0;
        __syncthreads();
        uint64_t prefix = s_prefix;
        for (int i = t; i < NA; i += 1024) {
            uint64_t key = ((uint64_t)ob[i] << 32) | (uint64_t)(0xFFFFFFFFu - (uint32_t)i);
            bool match = (pass == 0) || (((key ^ prefix) >> (64 - 8 * pass)) == 0);
            if (match) atomicAdd(&hist[(uint32_t)(key >> shift) & 255u], 1u);
        }
        __syncthreads();
        if (t == 0) {
            int k = s_k; uint32_t cum = 0; int d = 255;
            for (; d >= 0; --d) {
                uint32_t c = hist[d];
                if (cum + c >= (uint32_t)k) break;
                cum += c;
            }
            s_k = k - (int)cum;
            s_prefix = prefix | ((uint64_t)(uint32_t)d << shift);
        }
        __syncthreads();
    }

    // compact keys >= K*  (exactly 1000 by uniqueness)
    uint64_t kstar = s_prefix;
    for (int i = t; i < NA; i += 1024) {
        uint64_t key = ((uint64_t)ob[i] << 32) | (uint64_t)(0xFFFFFFFFu - (uint32_t)i);
        if (key >= kstar) {
            int p = atomicAdd(&s_cnt, 1);
            if (p < 1024) sbuf[p] = key;
        }
    }
    __syncthreads();

    // bitonic sort 1024 descending
    for (int k = 2; k <= 1024; k <<= 1) {
        for (int j = k >> 1; j > 0; j >>= 1) {
            int ixj = t ^ j;
            if (ixj > t) {
                uint64_t A = sbuf[t], Bv = sbuf[ixj];
                bool descBlock = ((t & k) == 0);
                bool sw = descBlock ? (A < Bv) : (A > Bv);
                if (sw) { sbuf[t] = Bv; sbuf[ixj] = A; }
            }
            __syncthreads();
        }
    }

    if (t < PRE_TOPK) {
        uint64_t key = sbuf[t];
        uint32_t u = (uint32_t)(key >> 32);
        uint32_t fb = (u & 0x80000000u) ? (u ^ 0x80000000u) : ~u;
        float val = __uint_as_float(fb);
        int idx = (int)(0xFFFFFFFFu - (uint32_t)(key & 0xFFFFFFFFull));
        size_t g = (size_t)b * NA + idx;
        float cx = box[g * 4 + 0], cy = box[g * 4 + 1];
        float w  = box[g * 4 + 2], h  = box[g * 4 + 3];
        size_t o = (size_t)b * PRE_TOPK + t;
        topv[o] = val;
        bxyxy[o * 4 + 0] = cx - w * 0.5f;
        bxyxy[o * 4 + 1] = cy - h * 0.5f;
        bxyxy[o * 4 + 2] = cx + w * 0.5f;
        bxyxy[o * 4 + 3] = cy + h * 0.5f;
        topcls[o] = clsid[g];
    }
}

// ---------------- Kernel 3: pairwise IoU suppression bitmask ----------------
__global__ __launch_bounds__(256) void k_iou(
    const float* __restrict__ bxyxy, unsigned long long* __restrict__ mask)
{
    __shared__ float4 boxes[PRE_TOPK];   // 16 KB
    int b = blockIdx.y;
    int t = threadIdx.x;
    const float4* bp = (const float4*)(bxyxy + (size_t)b * PRE_TOPK * 4);
    for (int i = t; i < PRE_TOPK; i += 256) boxes[i] = bp[i];
    __syncthreads();

    int r_local = t >> 4, w = t & 15;
    int row = blockIdx.x * 16 + r_local;
    if (row >= PRE_TOPK) return;

    float4 bi = boxes[row];
    float area_i = (bi.z - bi.x) * (bi.w - bi.y);
    unsigned long long bits = 0;
    int j0 = w * 64;
    #pragma unroll 4
    for (int jj = 0; jj < 64; ++jj) {
        int j = j0 + jj;
        if (j >= PRE_TOPK) break;
        if (j <= row) continue;
        float4 bj = boxes[j];
        float lx = fmaxf(bi.x, bj.x), ly = fmaxf(bi.y, bj.y);
        float rx = fminf(bi.z, bj.z), ry = fminf(bi.w, bj.w);
        float iw = fmaxf(rx - lx, 0.f), ih = fmaxf(ry - ly, 0.f);
        float inter = iw * ih;
        float area_j = (bj.z - bj.x) * (bj.w - bj.y);
        float iou = inter / (area_i + area_j - inter + 1e-7f);
        if (iou > 0.45f) bits |= (1ull << jj);
    }
    mask[((size_t)b * PRE_TOPK + row) * 16 + w] = bits;
}

// ---------------- Kernel 4: sequential NMS walk + emit top-100 ----------------
#define CHUNK 125
__global__ __launch_bounds__(256) void k_nms(
    const unsigned long long* __restrict__ mask, const float* __restrict__ topv,
    const float* __restrict__ bxyxy, const int* __restrict__ topcls,
    float* __restrict__ out)
{
    int b = blockIdx.x;
    int t = threadIdx.x;

    __shared__ unsigned long long mrows[CHUNK * 16];  // 16 KB
    __shared__ float sv[PRE_TOPK];                    // 4 KB
    __shared__ int kept[MAX_DET];
    __shared__ unsigned long long s_supp[16];
    __shared__ int s_cnt;
    __shared__ int s_done;

    for (int i = t; i < PRE_TOPK; i += 256) sv[i] = topv[(size_t)b * PRE_TOPK + i];
    if (t == 0) { s_cnt = 0; s_done = 0; }
    if (t < 16) s_supp[t] = 0;
    __syncthreads();

    for (int c = 0; c < 8; ++c) {
        int base = c * CHUNK;
        // stage this chunk's mask rows
        for (int i = t; i < CHUNK * 16; i += 256) {
            int row = base + (i >> 4);
            if (row < PRE_TOPK)
                mrows[i] = mask[((size_t)b * PRE_TOPK + row) * 16 + (i & 15)];
        }
        __syncthreads();
        if (t < 64) {  // wave 0 does the sequential walk
            unsigned long long supp = (t < 16) ? s_supp[t] : 0ull;
            int cnt = s_cnt;
            int end = base + CHUNK;
            for (int i = base; i < end; ++i) {
                int wsel = i >> 6, bit = i & 63;
                int sbit = (int)((supp >> bit) & 1ull);
                sbit = __shfl(sbit, wsel);
                bool keep = (!sbit) && (sv[i] > 0.0f);
                if (keep) {
                    if (t < 16) supp |= mrows[(i - base) * 16 + t];
                    if (t == 0 && cnt < MAX_DET) kept[cnt] = i;
                    ++cnt;
                }
            }
            if (t < 16) s_supp[t] = supp;
            if (t == 0) { s_cnt = cnt; if (cnt >= MAX_DET) s_done = 1; }
        }
        __syncthreads();
        if (s_done) break;  // uniform: written before the barrier
    }

    // emit outputs (whole flat buffer as float32)
    int cnt = s_cnt; if (cnt > MAX_DET) cnt = MAX_DET;
    if (t == 0) out[b] = (float)cnt;                       // num_dets (B,1)
    if (t < MAX_DET) {
        bool valid = t < cnt;
        float bx0 = 0.f, bx1 = 0.f, bx2 = 0.f, bx3 = 0.f, sc = 0.f, cl = 0.f;
        if (valid) {
            int p = kept[t];
            size_t o = (size_t)b * PRE_TOPK + p;
            sc = sv[p];
            bx0 = bxyxy[o * 4 + 0];
            bx1 = bxyxy[o * 4 + 1];
            bx2 = bxyxy[o * 4 + 2];
            bx3 = bxyxy[o * 4 + 3];
            cl = (float)topcls[o];
        }
        size_t db = 32 + ((size_t)b * MAX_DET + t) * 4;
        out[db + 0] = bx0; out[db + 1] = bx1; out[db + 2] = bx2; out[db + 3] = bx3;
        out[32 + 12800 + (size_t)b * MAX_DET + t] = sc;    // det_scores
        out[32 + 16000 + (size_t)b * MAX_DET + t] = cl;    // det_classes
    }
}

// ---------------- launch ----------------
extern "C" void kernel_launch(void* const* d_in, const int* in_sizes, int n_in,
                              void* d_out, int out_size, void* d_ws, size_t ws_size,
                              hipStream_t stream)
{
    const float* p3 = (const float*)d_in[0];
    const float* p4 = (const float*)d_in[1];
    const float* p5 = (const float*)d_in[2];
    float* out = (float*)d_out;

    char* ws = (char*)d_ws;
    // layout (bytes), masks first for 8B alignment
    size_t off_mask = 0;                                   // 32*1000*16*8 = 4,096,000
    size_t off_conf = off_mask + (size_t)NB * PRE_TOPK * 16 * 8;
    size_t off_cls  = off_conf + (size_t)NB * NA * 4;
    size_t off_box  = off_cls  + (size_t)NB * NA * 4;
    size_t off_topv = off_box  + (size_t)NB * NA * 4 * 4;
    size_t off_topc = off_topv + (size_t)NB * PRE_TOPK * 4;
    size_t off_bx   = off_topc + (size_t)NB * PRE_TOPK * 4;

    unsigned long long* mask = (unsigned long long*)(ws + off_mask);
    float* conf   = (float*)(ws + off_conf);
    int*   clsid  = (int*)(ws + off_cls);
    float* box    = (float*)(ws + off_box);
    float* topv   = (float*)(ws + off_topv);
    int*   topcls = (int*)(ws + off_topc);
    float* bxyxy  = (float*)(ws + off_bx);

    int total = NB * NA;
    k_decode<<<(total + 255) / 256, 256, 0, stream>>>(p3, p4, p5, conf, clsid, box);
    k_topk<<<NB, 1024, 0, stream>>>(conf, box, clsid, topv, bxyxy, topcls);
    k_iou<<<dim3((PRE_TOPK + 15) / 16, NB), 256, 0, stream>>>(bxyxy, mask);
    k_nms<<<NB, 256, 0, stream>>>(mask, topv, bxyxy, topcls, out);
}

// Round 2
// 158.899 us; speedup vs baseline: 1.5652x; 1.5652x over previous
//
#include <hip/hip_runtime.h>
#include <math.h>

#define NCLS 80
#define NA 8400
#define NB 32
#define NO 144
#define PRE_TOPK 1000
#define MAX_DET 100

// ---------------- Kernel 1: decode (DFL + max-logit sigmoid) ----------------
// One thread per (batch, anchor). Per-level template so the channel stride is
// a compile-time constant; all 144 loads issued before compute (latency batching).
template<int HW, int WDIM, int S>
__device__ __forceinline__ void decode_store(
    const float* __restrict__ src, int g, int aoff,
    float* __restrict__ conf, int* __restrict__ clsid, float* __restrict__ box)
{
    int b = g / HW;
    int pos = g - b * HW;
    float ax = (float)(pos % WDIM) + 0.5f;
    float ay = (float)(pos / WDIM) + 0.5f;
    const float* base = src + (size_t)b * (NO * HW) + pos;

    // issue all DFL loads
    float vd[64];
    #pragma unroll
    for (int i = 0; i < 64; ++i) vd[i] = base[(size_t)i * HW];

    // issue all class loads
    float vc[80];
    #pragma unroll
    for (int c = 0; c < 80; ++c) vc[c] = base[(size_t)(64 + c) * HW];

    // argmax over logits, 4 independent chains of 20 (first-occurrence ties)
    float m0 = vc[0];  int i0 = 0;
    float m1 = vc[20]; int i1 = 20;
    float m2 = vc[40]; int i2 = 40;
    float m3 = vc[60]; int i3 = 60;
    #pragma unroll
    for (int c = 1; c < 20; ++c) {
        if (vc[c]      > m0) { m0 = vc[c];      i0 = c;      }
        if (vc[20 + c] > m1) { m1 = vc[20 + c]; i1 = 20 + c; }
        if (vc[40 + c] > m2) { m2 = vc[40 + c]; i2 = 40 + c; }
        if (vc[60 + c] > m3) { m3 = vc[60 + c]; i3 = 60 + c; }
    }
    // combine in order (lower chunk wins ties -> first occurrence)
    float m = m0; int bid = i0;
    if (m1 > m) { m = m1; bid = i1; }
    if (m2 > m) { m = m2; bid = i2; }
    if (m3 > m) { m = m3; bid = i3; }
    float conf_v = 1.0f / (1.0f + __expf(-m));   // max(sigmoid) == sigmoid(max)

    // DFL: softmax over 16 bins per side, dot with arange(16)
    float dist[4];
    #pragma unroll
    for (int s4 = 0; s4 < 4; ++s4) {
        float mm = vd[s4 * 16];
        #pragma unroll
        for (int r = 1; r < 16; ++r) mm = fmaxf(mm, vd[s4 * 16 + r]);
        float e[16]; float sum = 0.f;
        #pragma unroll
        for (int r = 0; r < 16; ++r) { e[r] = __expf(vd[s4 * 16 + r] - mm); sum += e[r]; }
        float inv = 1.0f / sum;
        float d = 0.f;
        #pragma unroll
        for (int r = 1; r < 16; ++r) d += (e[r] * inv) * (float)r;
        dist[s4] = d;
    }

    float x1 = ax - dist[0], y1 = ay - dist[1];
    float x2 = ax + dist[2], y2 = ay + dist[3];
    float cx = ((x1 + x2) * 0.5f) * (float)S;
    float cy = ((y1 + y2) * 0.5f) * (float)S;
    float w  = (x2 - x1) * (float)S;
    float h  = (y2 - y1) * (float)S;

    size_t gid = (size_t)b * NA + aoff + pos;
    conf[gid]  = conf_v;
    clsid[gid] = bid;
    *(float4*)(box + gid * 4) = make_float4(cx, cy, w, h);
}

__global__ __launch_bounds__(256) void k_decode(
    const float* __restrict__ p3, const float* __restrict__ p4, const float* __restrict__ p5,
    float* __restrict__ conf, int* __restrict__ clsid, float* __restrict__ box)
{
    int blk = blockIdx.x;
    int t = threadIdx.x;
    if (blk < 800) {            // p3: 32 * 6400 = 204800 threads
        int g = blk * 256 + t;
        decode_store<6400, 80, 8>(p3, g, 0, conf, clsid, box);
    } else if (blk < 1000) {    // p4: 32 * 1600 = 51200 threads
        int g = (blk - 800) * 256 + t;
        decode_store<1600, 40, 16>(p4, g, 6400, conf, clsid, box);
    } else {                    // p5: 32 * 400 = 12800 threads
        int g = (blk - 1000) * 256 + t;
        decode_store<400, 20, 32>(p5, g, 8000, conf, clsid, box);
    }
}

// ---------------- Kernel 2: exact stable top-1000 per batch ----------------
__device__ __forceinline__ uint32_t ord_bits(float f) {
    uint32_t u = __float_as_uint(f);
    return (u & 0x80000000u) ? ~u : (u | 0x80000000u);
}

__global__ __launch_bounds__(1024) void k_topk(
    const float* __restrict__ conf, const float* __restrict__ box, const int* __restrict__ clsid,
    float* __restrict__ topv, float* __restrict__ bxyxy, int* __restrict__ topcls)
{
    int b = blockIdx.x;
    int t = threadIdx.x;

    __shared__ uint32_t ob[NA];          // 33.6 KB
    __shared__ uint32_t hist[256];
    __shared__ uint64_t sbuf[1024];      // 8 KB
    __shared__ uint64_t s_prefix;
    __shared__ int s_k;
    __shared__ int s_cnt;

    const float* cf = conf + (size_t)b * NA;
    for (int i = t; i < NA; i += 1024) {
        float c = cf[i];
        float cm = (c > 0.25f) ? c : -1.0f;
        ob[i] = ord_bits(cm);
    }
    if (t == 0) { s_prefix = 0; s_k = PRE_TOPK; s_cnt = 0; }
    sbuf[t] = 0;
    __syncthreads();

    // radix-select the exact rank-1000 key (keys unique: index embedded)
    for (int pass = 0; pass < 8; ++pass) {
        int shift = 56 - 8 * pass;
        if (t < 256) hist[t] = 0;
        __syncthreads();
        uint64_t prefix = s_prefix;
        int k = s_k;
        for (int i = t; i < NA; i += 1024) {
            uint64_t key = ((uint64_t)ob[i] << 32) | (uint64_t)(0xFFFFFFFFu - (uint32_t)i);
            bool match = (pass == 0) || (((key ^ prefix) >> (64 - 8 * pass)) == 0);
            if (match) atomicAdd(&hist[(uint32_t)(key >> shift) & 255u], 1u);
        }
        __syncthreads();
        // wave-0 suffix-scan digit selection (replaces serial 256-bin walk)
        if (t < 64) {
            uint32_t h0 = hist[4 * t + 0], h1 = hist[4 * t + 1];
            uint32_t h2 = hist[4 * t + 2], h3 = hist[4 * t + 3];
            uint32_t part = h0 + h1 + h2 + h3;
            uint32_t s = part;
            #pragma unroll
            for (int off = 1; off < 64; off <<= 1) {
                uint32_t v = __shfl_down(s, off);
                if (t + off < 64) s += v;
            }
            // s = sum over lanes >= t; cum_before(d) = count of keys in bins > d
            uint32_t cb3 = s - part;
            uint32_t cb2 = cb3 + h3;
            uint32_t cb1 = cb2 + h2;
            uint32_t cb0 = cb1 + h1;
            uint32_t ku = (uint32_t)k;
            if (cb3 < ku && ku <= cb3 + h3) { s_k = k - (int)cb3; s_prefix = prefix | ((uint64_t)(uint32_t)(4 * t + 3) << shift); }
            if (cb2 < ku && ku <= cb2 + h2) { s_k = k - (int)cb2; s_prefix = prefix | ((uint64_t)(uint32_t)(4 * t + 2) << shift); }
            if (cb1 < ku && ku <= cb1 + h1) { s_k = k - (int)cb1; s_prefix = prefix | ((uint64_t)(uint32_t)(4 * t + 1) << shift); }
            if (cb0 < ku && ku <= cb0 + h0) { s_k = k - (int)cb0; s_prefix = prefix | ((uint64_t)(uint32_t)(4 * t + 0) << shift); }
        }
        __syncthreads();
    }

    // compact keys >= K*  (exactly 1000 by key uniqueness)
    uint64_t kstar = s_prefix;
    for (int i = t; i < NA; i += 1024) {
        uint64_t key = ((uint64_t)ob[i] << 32) | (uint64_t)(0xFFFFFFFFu - (uint32_t)i);
        if (key >= kstar) {
            int p = atomicAdd(&s_cnt, 1);
            if (p < 1024) sbuf[p] = key;
        }
    }
    __syncthreads();

    // bitonic sort 1024 descending
    for (int k = 2; k <= 1024; k <<= 1) {
        for (int j = k >> 1; j > 0; j >>= 1) {
            int ixj = t ^ j;
            if (ixj > t) {
                uint64_t A = sbuf[t], Bv = sbuf[ixj];
                bool descBlock = ((t & k) == 0);
                bool sw = descBlock ? (A < Bv) : (A > Bv);
                if (sw) { sbuf[t] = Bv; sbuf[ixj] = A; }
            }
            __syncthreads();
        }
    }

    if (t < PRE_TOPK) {
        uint64_t key = sbuf[t];
        uint32_t u = (uint32_t)(key >> 32);
        uint32_t fb = (u & 0x80000000u) ? (u ^ 0x80000000u) : ~u;
        float val = __uint_as_float(fb);
        int idx = (int)(0xFFFFFFFFu - (uint32_t)(key & 0xFFFFFFFFull));
        size_t g = (size_t)b * NA + idx;
        float cx = box[g * 4 + 0], cy = box[g * 4 + 1];
        float w  = box[g * 4 + 2], h  = box[g * 4 + 3];
        size_t o = (size_t)b * PRE_TOPK + t;
        topv[o] = val;
        bxyxy[o * 4 + 0] = cx - w * 0.5f;
        bxyxy[o * 4 + 1] = cy - h * 0.5f;
        bxyxy[o * 4 + 2] = cx + w * 0.5f;
        bxyxy[o * 4 + 3] = cy + h * 0.5f;
        topcls[o] = clsid[g];
    }
}

// ---------------- Kernel 3: pairwise IoU suppression bitmask ----------------
__global__ __launch_bounds__(256) void k_iou(
    const float* __restrict__ bxyxy, unsigned long long* __restrict__ mask)
{
    __shared__ float4 boxes[PRE_TOPK];   // 16 KB
    int b = blockIdx.y;
    int t = threadIdx.x;
    const float4* bp = (const float4*)(bxyxy + (size_t)b * PRE_TOPK * 4);
    for (int i = t; i < PRE_TOPK; i += 256) boxes[i] = bp[i];
    __syncthreads();

    int r_local = t >> 4, w = t & 15;
    int row = blockIdx.x * 16 + r_local;
    if (row >= PRE_TOPK) return;

    float4 bi = boxes[row];
    float area_i = (bi.z - bi.x) * (bi.w - bi.y);
    unsigned long long bits = 0;
    int j0 = w * 64;
    #pragma unroll 4
    for (int jj = 0; jj < 64; ++jj) {
        int j = j0 + jj;
        if (j >= PRE_TOPK) break;
        if (j <= row) continue;
        float4 bj = boxes[j];
        float lx = fmaxf(bi.x, bj.x), ly = fmaxf(bi.y, bj.y);
        float rx = fminf(bi.z, bj.z), ry = fminf(bi.w, bj.w);
        float iw = fmaxf(rx - lx, 0.f), ih = fmaxf(ry - ly, 0.f);
        float inter = iw * ih;
        float area_j = (bj.z - bj.x) * (bj.w - bj.y);
        float iou = inter / (area_i + area_j - inter + 1e-7f);
        if (iou > 0.45f) bits |= (1ull << jj);
    }
    mask[((size_t)b * PRE_TOPK + row) * 16 + w] = bits;
}

// ---------------- Kernel 4: sequential NMS walk + emit top-100 ----------------
#define CHUNK 125
__global__ __launch_bounds__(256) void k_nms(
    const unsigned long long* __restrict__ mask, const float* __restrict__ topv,
    const float* __restrict__ bxyxy, const int* __restrict__ topcls,
    float* __restrict__ out)
{
    int b = blockIdx.x;
    int t = threadIdx.x;

    __shared__ unsigned long long mrows[CHUNK * 16];  // 16 KB
    __shared__ float sv[PRE_TOPK];                    // 4 KB
    __shared__ int kept[MAX_DET];
    __shared__ unsigned long long s_supp[16];
    __shared__ int s_cnt;
    __shared__ int s_done;

    for (int i = t; i < PRE_TOPK; i += 256) sv[i] = topv[(size_t)b * PRE_TOPK + i];
    if (t == 0) { s_cnt = 0; s_done = 0; }
    if (t < 16) s_supp[t] = 0;
    __syncthreads();

    for (int c = 0; c < 8; ++c) {
        int base = c * CHUNK;
        for (int i = t; i < CHUNK * 16; i += 256) {
            int row = base + (i >> 4);
            if (row < PRE_TOPK)
                mrows[i] = mask[((size_t)b * PRE_TOPK + row) * 16 + (i & 15)];
        }
        __syncthreads();
        if (t < 64) {  // wave 0 does the sequential walk
            unsigned long long supp = (t < 16) ? s_supp[t] : 0ull;
            int cnt = s_cnt;
            int end = base + CHUNK;
            for (int i = base; i < end; ++i) {
                int wsel = i >> 6, bit = i & 63;
                int sbit = (int)((supp >> bit) & 1ull);
                sbit = __shfl(sbit, wsel);
                bool keep = (!sbit) && (sv[i] > 0.0f);
                if (keep) {
                    if (t < 16) supp |= mrows[(i - base) * 16 + t];
                    if (t == 0 && cnt < MAX_DET) kept[cnt] = i;
                    ++cnt;
                }
            }
            if (t < 16) s_supp[t] = supp;
            if (t == 0) { s_cnt = cnt; if (cnt >= MAX_DET) s_done = 1; }
        }
        __syncthreads();
        if (s_done) break;
    }

    int cnt = s_cnt; if (cnt > MAX_DET) cnt = MAX_DET;
    if (t == 0) out[b] = (float)cnt;                       // num_dets (B,1)
    if (t < MAX_DET) {
        bool valid = t < cnt;
        float bx0 = 0.f, bx1 = 0.f, bx2 = 0.f, bx3 = 0.f, sc = 0.f, cl = 0.f;
        if (valid) {
            int p = kept[t];
            size_t o = (size_t)b * PRE_TOPK + p;
            sc = sv[p];
            bx0 = bxyxy[o * 4 + 0];
            bx1 = bxyxy[o * 4 + 1];
            bx2 = bxyxy[o * 4 + 2];
            bx3 = bxyxy[o * 4 + 3];
            cl = (float)topcls[o];
        }
        size_t db = 32 + ((size_t)b * MAX_DET + t) * 4;
        out[db + 0] = bx0; out[db + 1] = bx1; out[db + 2] = bx2; out[db + 3] = bx3;
        out[32 + 12800 + (size_t)b * MAX_DET + t] = sc;    // det_scores
        out[32 + 16000 + (size_t)b * MAX_DET + t] = cl;    // det_classes
    }
}

// ---------------- launch ----------------
extern "C" void kernel_launch(void* const* d_in, const int* in_sizes, int n_in,
                              void* d_out, int out_size, void* d_ws, size_t ws_size,
                              hipStream_t stream)
{
    const float* p3 = (const float*)d_in[0];
    const float* p4 = (const float*)d_in[1];
    const float* p5 = (const float*)d_in[2];
    float* out = (float*)d_out;

    char* ws = (char*)d_ws;
    size_t off_mask = 0;                                   // 32*1000*16*8 = 4,096,000
    size_t off_conf = off_mask + (size_t)NB * PRE_TOPK * 16 * 8;
    size_t off_cls  = off_conf + (size_t)NB * NA * 4;
    size_t off_box  = off_cls  + (size_t)NB * NA * 4;
    size_t off_topv = off_box  + (size_t)NB * NA * 4 * 4;
    size_t off_topc = off_topv + (size_t)NB * PRE_TOPK * 4;
    size_t off_bx   = off_topc + (size_t)NB * PRE_TOPK * 4;

    unsigned long long* mask = (unsigned long long*)(ws + off_mask);
    float* conf   = (float*)(ws + off_conf);
    int*   clsid  = (int*)(ws + off_cls);
    float* box    = (float*)(ws + off_box);
    float* topv   = (float*)(ws + off_topv);
    int*   topcls = (int*)(ws + off_topc);
    float* bxyxy  = (float*)(ws + off_bx);

    k_decode<<<1050, 256, 0, stream>>>(p3, p4, p5, conf, clsid, box);
    k_topk<<<NB, 1024, 0, stream>>>(conf, box, clsid, topv, bxyxy, topcls);
    k_iou<<<dim3((PRE_TOPK + 15) / 16, NB), 256, 0, stream>>>(bxyxy, mask);
    k_nms<<<NB, 256, 0, stream>>>(mask, topv, bxyxy, topcls, out);
}